// Round 3
// baseline (544.103 us; speedup 1.0000x reference)
//
#include <hip/hip_runtime.h>
#include <stdint.h>

#define BB 4096
#define TT 512
#define II 4
#define HH 32
#define SS 4

// 32 lanes per batch element (lane j owns h[j]); 2 batches per wave; 4 waves/block.
// All cross-lane traffic via register shuffles (no LDS, no ordering hazards).
__global__ __launch_bounds__(256, 2) void gru_kernel(
    const float* __restrict__ x, const float* __restrict__ h0,
    const float* __restrict__ w_ih, const float* __restrict__ w_hh,
    const float* __restrict__ b_ih, const float* __restrict__ b_hh,
    const float* __restrict__ w_proj, const float* __restrict__ b_proj,
    float* __restrict__ out) {
  const int tid  = threadIdx.x;
  const int wid  = tid >> 6;        // wave in block 0..3
  const int lane = tid & 63;
  const int g    = lane >> 5;       // which batch of the wave's two
  const int j    = lane & 31;       // h index owned by this lane
  const int b    = blockIdx.x * 8 + wid * 2 + g;

  // ---- preload weights into registers (reused 512x) ----
  const float4* whh4 = (const float4*)w_hh;      // [96][8] float4
  float wrf[HH], wzf[HH], wnf[HH];
#pragma unroll
  for (int c = 0; c < 8; ++c) {
    float4 a = whh4[(0 * HH + j) * 8 + c];
    float4 bq = whh4[(1 * HH + j) * 8 + c];
    float4 cq = whh4[(2 * HH + j) * 8 + c];
    wrf[4*c+0] = a.x;  wrf[4*c+1] = a.y;  wrf[4*c+2] = a.z;  wrf[4*c+3] = a.w;
    wzf[4*c+0] = bq.x; wzf[4*c+1] = bq.y; wzf[4*c+2] = bq.z; wzf[4*c+3] = bq.w;
    wnf[4*c+0] = cq.x; wnf[4*c+1] = cq.y; wnf[4*c+2] = cq.z; wnf[4*c+3] = cq.w;
  }
  const float4* wih4 = (const float4*)w_ih;      // each row is one float4 (I=4)
  const float4 wir = wih4[0 * HH + j];
  const float4 wiz = wih4[1 * HH + j];
  const float4 win = wih4[2 * HH + j];
  const float bir = b_ih[0 * HH + j], biz = b_ih[1 * HH + j], bin_ = b_ih[2 * HH + j];
  const float bhr = b_hh[0 * HH + j], bhz = b_hh[1 * HH + j], bhn = b_hh[2 * HH + j];

  const int s_idx = j & 3;          // output channel this lane reduces
  const int c_idx = j >> 2;         // h-chunk (of 4) this lane covers
  const float4* wp4 = (const float4*)w_proj;     // [4][8] float4
  const float4 wp = wp4[s_idx * 8 + c_idx];
  const float bp = b_proj[s_idx];

  float h_self = h0[(size_t)b * HH + j];

  const float4* xp = (const float4*)(x + (size_t)b * TT * II);  // 512 float4
  float* outp = out + (size_t)b * TT * SS;

  float4 xv = xp[0];

  for (int t = 0; t < TT; ++t) {
    float4 xvn = xp[(t + 1 < TT) ? (t + 1) : t];

    // input-gate contributions (I=4)
    float xr = fmaf(wir.x, xv.x, fmaf(wir.y, xv.y, fmaf(wir.z, xv.z, fmaf(wir.w, xv.w, bir))));
    float xz = fmaf(wiz.x, xv.x, fmaf(wiz.y, xv.y, fmaf(wiz.z, xv.z, fmaf(wiz.w, xv.w, biz))));
    float xn = fmaf(win.x, xv.x, fmaf(win.y, xv.y, fmaf(win.z, xv.z, fmaf(win.w, xv.w, bin_))));

    // hidden-gate contributions: shuffle-broadcast h across the 32-lane group
    float hr = bhr, hz = bhz, hn = bhn;
#pragma unroll
    for (int k = 0; k < HH; ++k) {
      const float hk = __shfl(h_self, k, 32);   // group-local broadcast of h[k]
      hr = fmaf(wrf[k], hk, hr);
      hz = fmaf(wzf[k], hk, hz);
      hn = fmaf(wnf[k], hk, hn);
    }

    const float r  = 1.0f / (1.0f + expf(-(xr + hr)));
    const float zz = 1.0f / (1.0f + expf(-(xz + hz)));
    const float nn = tanhf(fmaf(r, hn, xn));
    const float hnew = fmaf(zz, h_self - nn, nn);  // (1-z)n + z h
    h_self = hnew;

    // projection: lane j covers chunk c_idx of channel s_idx
    const float hc0 = __shfl(hnew, c_idx * 4 + 0, 32);
    const float hc1 = __shfl(hnew, c_idx * 4 + 1, 32);
    const float hc2 = __shfl(hnew, c_idx * 4 + 2, 32);
    const float hc3 = __shfl(hnew, c_idx * 4 + 3, 32);
    float v = fmaf(wp.x, hc0, fmaf(wp.y, hc1, fmaf(wp.z, hc2, wp.w * hc3)));
    // xor-butterfly over the 8 chunks (stays within each 32-lane group)
    v += __shfl_xor(v, 4, 64);
    v += __shfl_xor(v, 8, 64);
    v += __shfl_xor(v, 16, 64);
    if (c_idx == 0) {
      outp[t * SS + s_idx] = v + bp;
    }

    xv = xvn;
  }

  // hn output: [1, B, H] appended after state (float32)
  out[(size_t)BB * TT * SS + (size_t)b * HH + j] = h_self;
}

extern "C" void kernel_launch(void* const* d_in, const int* in_sizes, int n_in,
                              void* d_out, int out_size, void* d_ws, size_t ws_size,
                              hipStream_t stream) {
  const float* x      = (const float*)d_in[0];
  const float* h0     = (const float*)d_in[1];
  const float* w_ih   = (const float*)d_in[2];
  const float* w_hh   = (const float*)d_in[3];
  const float* b_ih   = (const float*)d_in[4];
  const float* b_hh   = (const float*)d_in[5];
  const float* w_proj = (const float*)d_in[6];
  const float* b_proj = (const float*)d_in[7];
  float* out = (float*)d_out;

  dim3 grid(BB / 8), block(256);
  hipLaunchKernelGGL(gru_kernel, grid, block, 0, stream,
                     x, h0, w_ih, w_hh, b_ih, b_hh, w_proj, b_proj, out);
}

// Round 4
// 332.529 us; speedup vs baseline: 1.6363x; 1.6363x over previous
//
#include <hip/hip_runtime.h>
#include <stdint.h>

#define BB 4096
#define TT 512
#define II 4
#define HH 32
#define SS 4

__device__ __forceinline__ float fast_sigm(float a) {
  return __builtin_amdgcn_rcpf(1.0f + __expf(-a));      // v_exp + v_rcp
}
__device__ __forceinline__ float fast_tanh(float y) {
  return 1.0f - 2.0f * __builtin_amdgcn_rcpf(__expf(2.0f * y) + 1.0f);
}

// 32 lanes per batch element (lane j owns h[j]); 2 batches per wave; 4 waves/block.
// h_{t-1} broadcast via one LDS row per batch: 1 ds_write + 9 broadcast ds_read_b128
// per timestep (vs 39 ds_bpermute in the shuffle version). Same-wave write->read,
// no barriers needed.
__global__ __launch_bounds__(256, 2) void gru_kernel(
    const float* __restrict__ x, const float* __restrict__ h0,
    const float* __restrict__ w_ih, const float* __restrict__ w_hh,
    const float* __restrict__ b_ih, const float* __restrict__ b_hh,
    const float* __restrict__ w_proj, const float* __restrict__ b_proj,
    float* __restrict__ out) {
  const int tid  = threadIdx.x;
  const int wid  = tid >> 6;        // wave in block 0..3
  const int lane = tid & 63;
  const int g    = lane >> 5;       // which batch of the wave's two
  const int j    = lane & 31;       // h index owned by this lane
  const int row  = wid * 2 + g;     // LDS row 0..7
  const int b    = blockIdx.x * 8 + row;

  // 8 rows x 36 floats: row stride 144 B (16B-aligned, +4-bank stagger per row)
  __shared__ float lds_h[8][36];
  float* lrow = &lds_h[row][0];

  // ---- preload weights into registers (reused 512x) ----
  const float4* whh4 = (const float4*)w_hh;      // [96][8] float4
  float4 wr[8], wz[8], wn[8];
#pragma unroll
  for (int c = 0; c < 8; ++c) {
    wr[c] = whh4[(0 * HH + j) * 8 + c];
    wz[c] = whh4[(1 * HH + j) * 8 + c];
    wn[c] = whh4[(2 * HH + j) * 8 + c];
  }
  const float4* wih4 = (const float4*)w_ih;      // each row is one float4 (I=4)
  const float4 wir = wih4[0 * HH + j];
  const float4 wiz = wih4[1 * HH + j];
  const float4 win = wih4[2 * HH + j];
  const float bir = b_ih[0 * HH + j], biz = b_ih[1 * HH + j], bin_ = b_ih[2 * HH + j];
  const float bhr = b_hh[0 * HH + j], bhz = b_hh[1 * HH + j], bhn = b_hh[2 * HH + j];

  const int s_idx = j & 3;          // output channel this lane reduces
  const int c_idx = j >> 2;         // h-chunk (of 4) this lane covers
  const float4* wp4 = (const float4*)w_proj;     // [4][8] float4
  const float4 wp = wp4[s_idx * 8 + c_idx];
  const float bp = b_proj[s_idx];

  float h_self = h0[(size_t)b * HH + j];
  lrow[j] = h_self;

  const float4* xp = (const float4*)(x + (size_t)b * TT * II);  // 512 float4
  float* outp = out + (size_t)b * TT * SS;

  float4 xv = xp[0];

  for (int t = 0; t < TT; ++t) {
    float4 xvn = xp[(t + 1 < TT) ? (t + 1) : t];

    // broadcast-read h_{t-1}: 8 x ds_read_b128, uniform addr per 32-lane group
    float4 ha[8];
#pragma unroll
    for (int c = 0; c < 8; ++c) ha[c] = *(const float4*)&lrow[c * 4];

    // input-gate contributions (I=4)
    float xr = fmaf(wir.x, xv.x, fmaf(wir.y, xv.y, fmaf(wir.z, xv.z, fmaf(wir.w, xv.w, bir))));
    float xz = fmaf(wiz.x, xv.x, fmaf(wiz.y, xv.y, fmaf(wiz.z, xv.z, fmaf(wiz.w, xv.w, biz))));
    float xn = fmaf(win.x, xv.x, fmaf(win.y, xv.y, fmaf(win.z, xv.z, fmaf(win.w, xv.w, bin_))));

    // hidden-gate contributions: 96 register-operand FMAs (3 independent chains)
    float hr = bhr, hz = bhz, hn = bhn;
#pragma unroll
    for (int c = 0; c < 8; ++c) {
      hr = fmaf(wr[c].x, ha[c].x, hr); hr = fmaf(wr[c].y, ha[c].y, hr);
      hr = fmaf(wr[c].z, ha[c].z, hr); hr = fmaf(wr[c].w, ha[c].w, hr);
      hz = fmaf(wz[c].x, ha[c].x, hz); hz = fmaf(wz[c].y, ha[c].y, hz);
      hz = fmaf(wz[c].z, ha[c].z, hz); hz = fmaf(wz[c].w, ha[c].w, hz);
      hn = fmaf(wn[c].x, ha[c].x, hn); hn = fmaf(wn[c].y, ha[c].y, hn);
      hn = fmaf(wn[c].z, ha[c].z, hn); hn = fmaf(wn[c].w, ha[c].w, hn);
    }

    const float r  = fast_sigm(xr + hr);
    const float zz = fast_sigm(xz + hz);
    const float nn = fast_tanh(fmaf(r, hn, xn));
    const float hnew = fmaf(zz, h_self - nn, nn);  // (1-z)n + z h
    h_self = hnew;

    // publish h_t (same-wave write then read; LDS pipe is in-order per wave)
    lrow[j] = hnew;

    // projection: lane j covers chunk c_idx of channel s_idx
    const float4 hc = *(const float4*)&lrow[c_idx * 4];
    float v = fmaf(wp.x, hc.x, fmaf(wp.y, hc.y, fmaf(wp.z, hc.z, wp.w * hc.w)));
    // xor-butterfly over the 8 chunks (stays within each 32-lane group)
    v += __shfl_xor(v, 4, 64);
    v += __shfl_xor(v, 8, 64);
    v += __shfl_xor(v, 16, 64);
    if (c_idx == 0) {
      outp[t * SS + s_idx] = v + bp;
    }

    xv = xvn;
  }

  // hn output: [1, B, H] appended after state (float32)
  out[(size_t)BB * TT * SS + (size_t)b * HH + j] = h_self;
}

extern "C" void kernel_launch(void* const* d_in, const int* in_sizes, int n_in,
                              void* d_out, int out_size, void* d_ws, size_t ws_size,
                              hipStream_t stream) {
  const float* x      = (const float*)d_in[0];
  const float* h0     = (const float*)d_in[1];
  const float* w_ih   = (const float*)d_in[2];
  const float* w_hh   = (const float*)d_in[3];
  const float* b_ih   = (const float*)d_in[4];
  const float* b_hh   = (const float*)d_in[5];
  const float* w_proj = (const float*)d_in[6];
  const float* b_proj = (const float*)d_in[7];
  float* out = (float*)d_out;

  dim3 grid(BB / 8), block(256);
  hipLaunchKernelGGL(gru_kernel, grid, block, 0, stream,
                     x, h0, w_ih, w_hh, b_ih, b_hh, w_proj, b_proj, out);
}

// Round 5
// 298.275 us; speedup vs baseline: 1.8242x; 1.1148x over previous
//
#include <hip/hip_runtime.h>
#include <stdint.h>

#define BB 4096
#define TT 512
#define II 4
#define HH 32
#define SS 4

__device__ __forceinline__ float fast_sigm(float a) {
  return __builtin_amdgcn_rcpf(1.0f + __expf(-a));      // v_exp + v_rcp
}
__device__ __forceinline__ float fast_tanh(float y) {
  return 1.0f - 2.0f * __builtin_amdgcn_rcpf(__expf(2.0f * y) + 1.0f);
}

// Force values to stay resident in VGPRs (defeats load-sinking/remat).
#define PIN8(A, base)                                                          \
  asm volatile("" : "+v"((A)[(base) + 0]), "+v"((A)[(base) + 1]),              \
                    "+v"((A)[(base) + 2]), "+v"((A)[(base) + 3]),              \
                    "+v"((A)[(base) + 4]), "+v"((A)[(base) + 5]),              \
                    "+v"((A)[(base) + 6]), "+v"((A)[(base) + 7]))

// 32 lanes per batch element (lane j owns h[j]); 2 batches per wave; 4 waves/block.
// h_{t-1} broadcast via one LDS row per batch (same-wave write->read, in-order DS
// pipe, no barriers). Projection for step t-1 is computed at the top of step t from
// the same broadcast reads, so the loop tail is just gates + one ds_write.
__global__ __launch_bounds__(256, 2) void gru_kernel(
    const float* __restrict__ x, const float* __restrict__ h0,
    const float* __restrict__ w_ih, const float* __restrict__ w_hh,
    const float* __restrict__ b_ih, const float* __restrict__ b_hh,
    const float* __restrict__ w_proj, const float* __restrict__ b_proj,
    float* __restrict__ out) {
  const int tid  = threadIdx.x;
  const int wid  = tid >> 6;        // wave in block 0..3
  const int lane = tid & 63;
  const int g    = lane >> 5;       // which batch of the wave's two
  const int j    = lane & 31;       // h index owned by this lane
  const int row  = wid * 2 + g;     // LDS row 0..7
  const int b    = blockIdx.x * 8 + row;

  // 8 rows x 36 floats: row stride 144 B -> the two lane-groups of a wave hit
  // disjoint bank sets on broadcast reads; writes are 2-way aliased (free).
  __shared__ float lds_h[8][36];
  float* lrow = &lds_h[row][0];

  // ---- preload weights into registers (reused 512x) ----
  const float4* whh4 = (const float4*)w_hh;      // [96][8] float4
  float wrf[HH], wzf[HH], wnf[HH];
#pragma unroll
  for (int c = 0; c < 8; ++c) {
    float4 a  = whh4[(0 * HH + j) * 8 + c];
    float4 bq = whh4[(1 * HH + j) * 8 + c];
    float4 cq = whh4[(2 * HH + j) * 8 + c];
    wrf[4*c+0] = a.x;  wrf[4*c+1] = a.y;  wrf[4*c+2] = a.z;  wrf[4*c+3] = a.w;
    wzf[4*c+0] = bq.x; wzf[4*c+1] = bq.y; wzf[4*c+2] = bq.z; wzf[4*c+3] = bq.w;
    wnf[4*c+0] = cq.x; wnf[4*c+1] = cq.y; wnf[4*c+2] = cq.z; wnf[4*c+3] = cq.w;
  }
  PIN8(wrf, 0); PIN8(wrf, 8); PIN8(wrf, 16); PIN8(wrf, 24);
  PIN8(wzf, 0); PIN8(wzf, 8); PIN8(wzf, 16); PIN8(wzf, 24);
  PIN8(wnf, 0); PIN8(wnf, 8); PIN8(wnf, 16); PIN8(wnf, 24);

  const float4* wih4 = (const float4*)w_ih;      // each row is one float4 (I=4)
  float wif[12];
  {
    float4 a = wih4[0 * HH + j], bq = wih4[1 * HH + j], cq = wih4[2 * HH + j];
    wif[0]=a.x;  wif[1]=a.y;  wif[2]=a.z;  wif[3]=a.w;
    wif[4]=bq.x; wif[5]=bq.y; wif[6]=bq.z; wif[7]=bq.w;
    wif[8]=cq.x; wif[9]=cq.y; wif[10]=cq.z; wif[11]=cq.w;
  }
  PIN8(wif, 0);
  asm volatile("" : "+v"(wif[8]), "+v"(wif[9]), "+v"(wif[10]), "+v"(wif[11]));

  float bir = b_ih[0*HH + j], biz = b_ih[1*HH + j], bin_ = b_ih[2*HH + j];
  float bhr = b_hh[0*HH + j], bhz = b_hh[1*HH + j], bhn = b_hh[2*HH + j];

  const int s_idx = j & 3;          // output channel this lane reduces
  const int c_idx = j >> 2;         // h-chunk (of 4) this lane covers
  const float4* wp4 = (const float4*)w_proj;     // [4][8] float4
  float wpf[4];
  {
    float4 p = wp4[s_idx * 8 + c_idx];
    wpf[0]=p.x; wpf[1]=p.y; wpf[2]=p.z; wpf[3]=p.w;
  }
  float bp = b_proj[s_idx];
  asm volatile("" : "+v"(wpf[0]), "+v"(wpf[1]), "+v"(wpf[2]), "+v"(wpf[3]),
                    "+v"(bir), "+v"(biz), "+v"(bin_), "+v"(bp));
  asm volatile("" : "+v"(bhr), "+v"(bhz), "+v"(bhn));

  float h_self = h0[(size_t)b * HH + j];
  lrow[j] = h_self;

  const float4* xp = (const float4*)(x + (size_t)b * TT * II);  // 512 float4
  float* outp = out + (size_t)b * TT * SS;
  const float* hc_addr = lrow + (c_idx << 2);    // loop-invariant per-lane address

  float4 xv = xp[0];

  for (int t = 0; t <= TT; ++t) {
    // broadcast-read h_{t-1}: 8 x ds_read_b128, uniform addr per 32-lane group,
    // plus this lane's projection chunk (per-lane static address).
    float4 ha[8];
#pragma unroll
    for (int c = 0; c < 8; ++c) ha[c] = *(const float4*)&lrow[c * 4];
    const float4 hcv = *(const float4*)hc_addr;

    // deferred projection: out[t-1] = proj(h_{t-1})
    if (t > 0) {
      float v = fmaf(wpf[0], hcv.x, fmaf(wpf[1], hcv.y,
                fmaf(wpf[2], hcv.z, wpf[3] * hcv.w)));
      v += __shfl_xor(v, 4, 64);
      v += __shfl_xor(v, 8, 64);
      v += __shfl_xor(v, 16, 64);
      if (c_idx == 0) {
        outp[(t - 1) * SS + s_idx] = v + bp;
      }
    }
    if (t == TT) break;

    float4 xvn = xp[(t + 1 < TT) ? (t + 1) : t];   // next-step x prefetch

    // input-gate contributions (I=4)
    float xr = fmaf(wif[0], xv.x, fmaf(wif[1], xv.y, fmaf(wif[2],  xv.z, fmaf(wif[3],  xv.w, bir))));
    float xz = fmaf(wif[4], xv.x, fmaf(wif[5], xv.y, fmaf(wif[6],  xv.z, fmaf(wif[7],  xv.w, biz))));
    float xn = fmaf(wif[8], xv.x, fmaf(wif[9], xv.y, fmaf(wif[10], xv.z, fmaf(wif[11], xv.w, bin_))));

    // hidden-gate contributions: 96 register-operand FMAs (3 independent chains)
    float hr = bhr, hz = bhz, hn = bhn;
#pragma unroll
    for (int c = 0; c < 8; ++c) {
      hr = fmaf(wrf[4*c+0], ha[c].x, hr); hr = fmaf(wrf[4*c+1], ha[c].y, hr);
      hr = fmaf(wrf[4*c+2], ha[c].z, hr); hr = fmaf(wrf[4*c+3], ha[c].w, hr);
      hz = fmaf(wzf[4*c+0], ha[c].x, hz); hz = fmaf(wzf[4*c+1], ha[c].y, hz);
      hz = fmaf(wzf[4*c+2], ha[c].z, hz); hz = fmaf(wzf[4*c+3], ha[c].w, hz);
      hn = fmaf(wnf[4*c+0], ha[c].x, hn); hn = fmaf(wnf[4*c+1], ha[c].y, hn);
      hn = fmaf(wnf[4*c+2], ha[c].z, hn); hn = fmaf(wnf[4*c+3], ha[c].w, hn);
    }

    const float r  = fast_sigm(xr + hr);
    const float zz = fast_sigm(xz + hz);
    const float nn = fast_tanh(fmaf(r, hn, xn));
    const float hnew = fmaf(zz, h_self - nn, nn);  // (1-z)n + z h
    h_self = hnew;

    // publish h_t (same-wave write then read next iteration; DS pipe in-order)
    lrow[j] = hnew;

    xv = xvn;
  }

  // hn output: [1, B, H] appended after state (float32)
  out[(size_t)BB * TT * SS + (size_t)b * HH + j] = h_self;
}

extern "C" void kernel_launch(void* const* d_in, const int* in_sizes, int n_in,
                              void* d_out, int out_size, void* d_ws, size_t ws_size,
                              hipStream_t stream) {
  const float* x      = (const float*)d_in[0];
  const float* h0     = (const float*)d_in[1];
  const float* w_ih   = (const float*)d_in[2];
  const float* w_hh   = (const float*)d_in[3];
  const float* b_ih   = (const float*)d_in[4];
  const float* b_hh   = (const float*)d_in[5];
  const float* w_proj = (const float*)d_in[6];
  const float* b_proj = (const float*)d_in[7];
  float* out = (float*)d_out;

  dim3 grid(BB / 8), block(256);
  hipLaunchKernelGGL(gru_kernel, grid, block, 0, stream,
                     x, h0, w_ih, w_hh, b_ih, b_hh, w_proj, b_proj, out);
}